// Round 2
// baseline (260.054 us; speedup 1.0000x reference)
//
#include <hip/hip_runtime.h>

#define G_    48
#define NPG_  128
#define NTOT_ 6144
#define D_    128
#define EPG_  4096
#define ETOT_ 196608

// element offsets into f32 d_out
#define OUT_ADJ  0ull
#define OUT_PERT 37748736ull
#define OUT_MASK 75497472ull
#define OUT_PRED 76283904ull

using short8 = __attribute__((ext_vector_type(8))) short;
using half8  = __attribute__((ext_vector_type(8))) _Float16;
using f32x4  = __attribute__((ext_vector_type(4))) float;
using float4v = __attribute__((ext_vector_type(4))) float;

__device__ __forceinline__ short f2h(float f) {
    _Float16 h = (_Float16)f;
    return __builtin_bit_cast(short, h);
}
__device__ __forceinline__ float h2f(short s) {
    _Float16 h = __builtin_bit_cast(_Float16, s);
    return (float)h;
}
__device__ __forceinline__ float ftanh(float x) {
    float ax = fabsf(x);
    float e = __expf(-2.0f * ax);
    float r = (1.0f - e) / (1.0f + e);
    return copysignf(r, x);
}

// ---------------------------------------------------------------------------
// Adjacency: per-graph LDS histogram -> f32 diag block of adjs_dense,
// fp16 adjT (adjT[g][d][s] = A[s][d]) and u8 counts for k_pert.
// ---------------------------------------------------------------------------
__global__ void __launch_bounds__(256) k_adj(const int* __restrict__ ei,
                                             float* __restrict__ out,
                                             short* __restrict__ adjT,
                                             unsigned char* __restrict__ a8)
{
    __shared__ unsigned int A[NPG_ * NPG_]; // 64 KB
    const int g = blockIdx.x, t = threadIdx.x;
    for (int i = t; i < NPG_ * NPG_; i += 256) A[i] = 0u;
    __syncthreads();
    const int* srcp = ei + g * EPG_;
    const int* dstp = ei + ETOT_ + g * EPG_;
    const int base = g * NPG_;
    for (int i = t; i < EPG_; i += 256) {
        int s = srcp[i] - base;
        int d = dstp[i] - base;
        atomicAdd(&A[s * NPG_ + d], 1u);
    }
    __syncthreads();
    for (int i = t; i < NPG_ * NPG_; i += 256) {
        int r = i >> 7, c = i & 127;
        unsigned int cnt = A[i];
        out[OUT_ADJ + (size_t)(base + r) * NTOT_ + base + c] = (float)cnt;
        adjT[g * NPG_ * NPG_ + c * NPG_ + r] = f2h((float)cnt); // exact (small ints)
        a8[g * NPG_ * NPG_ + i] = (unsigned char)cnt;
    }
}

// ---------------------------------------------------------------------------
// Perturbed adjacency: S = P_g @ A_g + Bp_g accumulated in f64 (sign-exact);
// pert_adj = (S > 0). Writes f32 0/1 + fp16 transposed copy for k_gin.
// ---------------------------------------------------------------------------
__global__ void __launch_bounds__(256) k_pert(const float* __restrict__ P,
                                              const float* __restrict__ Bp,
                                              const unsigned char* __restrict__ a8,
                                              float* __restrict__ out1,
                                              short* __restrict__ pertT)
{
    __shared__ unsigned char sA[NPG_ * NPG_]; // 16 KB, [k][j]
    const int g = blockIdx.x >> 3;
    const int i0 = (blockIdx.x & 7) * 16;
    const int t = threadIdx.x;
    const unsigned char* a = a8 + g * NPG_ * NPG_;
    for (int i = t * 4; i < NPG_ * NPG_; i += 1024)
        *(unsigned int*)&sA[i] = *(const unsigned int*)(a + i);
    __syncthreads();
    const int i = i0 + (t >> 4);
    const int j0 = (t & 15) * 8;
    const float* Prow = P + ((size_t)g * NPG_ + i) * NPG_;
    const float* Brow = Bp + ((size_t)g * NPG_ + i) * NPG_ + j0;
    double acc[8];
    #pragma unroll
    for (int jj = 0; jj < 8; jj++) acc[jj] = (double)Brow[jj];
    for (int k = 0; k < NPG_; k++) {
        double p = (double)Prow[k];
        const unsigned char* ar = &sA[k * NPG_ + j0];
        #pragma unroll
        for (int jj = 0; jj < 8; jj++) acc[jj] += p * (double)ar[jj];
    }
    const size_t obase = (size_t)(g * NPG_ + i) * NTOT_ + g * NPG_ + j0;
    #pragma unroll
    for (int jj = 0; jj < 8; jj++) {
        bool one = (acc[jj] > 0.0);
        out1[obase + jj] = one ? 1.0f : 0.0f;
        pertT[g * NPG_ * NPG_ + (j0 + jj) * NPG_ + i] = one ? (short)0x3C00 : (short)0;
    }
}

// ---------------------------------------------------------------------------
// mask = (M > 0) f32; also emit fp16 x and fp16 x_masked for the GIN runs.
// ---------------------------------------------------------------------------
__global__ void __launch_bounds__(256) k_mask(const float* __restrict__ x,
                                              const float* __restrict__ M,
                                              float* __restrict__ outm,
                                              short* __restrict__ xh,
                                              short* __restrict__ xmh)
{
    int idx = blockIdx.x * 256 + threadIdx.x;
    if (idx >= NTOT_ * D_ / 4) return;
    float4v mv = *(const float4v*)(M + idx * 4);
    float4v xv = *(const float4v*)(x + idx * 4);
    float4v om;
    short hx[4], hm[4];
    #pragma unroll
    for (int e = 0; e < 4; e++) {
        bool pos = (mv[e] > 0.0f);
        om[e] = pos ? 1.0f : 0.0f;
        hx[e] = f2h(xv[e]);
        hm[e] = pos ? hx[e] : (short)0;
    }
    *(float4v*)(outm + idx * 4) = om;
    *(unsigned long long*)(xh + idx * 4)  = *(unsigned long long*)hx;
    *(unsigned long long*)(xmh + idx * 4) = *(unsigned long long*)hm;
}

// ---------------------------------------------------------------------------
// Weight transpose+convert: WT(fp16) = [WaT(2,256,128)|WbT(2,256,256)|WcT(2,128,256)]
// ---------------------------------------------------------------------------
__global__ void __launch_bounds__(256) k_wt(const float* __restrict__ Wa,
                                            const float* __restrict__ Wb,
                                            const float* __restrict__ Wc,
                                            short* __restrict__ WT)
{
    int idx = blockIdx.x * 256 + threadIdx.x;
    if (idx < 65536) {                       // WaT[l][n<256][k<128] = Wa[l][k][n]
        int l = idx >> 15, r = idx & 32767;
        int n = r >> 7, k = r & 127;
        WT[idx] = f2h(Wa[l * 32768 + k * 256 + n]);
    } else if (idx < 196608) {               // WbT[l][n<256][k<256] = Wb[l][k][n]
        int j = idx - 65536;
        int l = j >> 16, r = j & 65535;
        int n = r >> 8, k = r & 255;
        WT[idx] = f2h(Wb[l * 65536 + k * 256 + n]);
    } else if (idx < 262144) {               // WcT[l][n<128][k<256] = Wc[l][k][n]
        int j = idx - 196608;
        int l = j >> 15, r = j & 32767;
        int n = r >> 8, k = r & 255;
        WT[idx] = f2h(Wc[l * 32768 + k * 128 + n]);
    }
}

// ---------------------------------------------------------------------------
// Fused GIN per (graph, run). 256 threads / 4 waves, 128 KB LDS (fp16 tiles).
// LDS map (shorts): h[0,16384) hT[16384,32768) z0[32768,49152)
//                   t1 -> [0,32768)  t2 -> [32768,65536)
// XOR swizzle on all tiles: k ^= (row&7)<<3 (kills stride-128/256 conflicts).
// MFMA layouts (16x16x32): A row=lane&15, k=(lane>>4)*8+e;  B col=lane&15,
// k=(lane>>4)*8+e;  C/D col=lane&15, row=(lane>>4)*4+reg.
// ---------------------------------------------------------------------------
template<int KS, int NN, int MODE>
__device__ __forceinline__ void fc_phase(short* S, int aoff, int lda, int outoff, int ldo,
                                         const short* __restrict__ BT,
                                         const float* __restrict__ bias,
                                         int w, int lr, int lh)
{
    short8 a[2][KS];
    #pragma unroll
    for (int m = 0; m < 2; m++) {
        int row = w * 32 + m * 16 + lr;
        #pragma unroll
        for (int ks = 0; ks < KS; ks++)
            a[m][ks] = *(const short8*)&S[aoff + row * lda + ((ks * 32 + lh * 8) ^ ((row & 7) << 3))];
    }
    for (int nt = 0; nt < NN / 16; nt++) {
        int col = nt * 16 + lr;
        f32x4 acc0 = {0.f, 0.f, 0.f, 0.f}, acc1 = {0.f, 0.f, 0.f, 0.f};
        #pragma unroll
        for (int ks = 0; ks < KS; ks++) {
            half8 bfr = __builtin_bit_cast(half8, *(const short8*)(BT + col * (KS * 32) + ks * 32 + lh * 8));
            acc0 = __builtin_amdgcn_mfma_f32_16x16x32_f16(__builtin_bit_cast(half8, a[0][ks]), bfr, acc0, 0, 0, 0);
            acc1 = __builtin_amdgcn_mfma_f32_16x16x32_f16(__builtin_bit_cast(half8, a[1][ks]), bfr, acc1, 0, 0, 0);
        }
        float bv = bias[col];
        #pragma unroll
        for (int m = 0; m < 2; m++) {
            f32x4 acc = m ? acc1 : acc0;
            #pragma unroll
            for (int r = 0; r < 4; r++) {
                int row = w * 32 + m * 16 + lh * 4 + r;
                float v = ftanh(acc[r] + bv);
                if (MODE == 0) {
                    S[outoff + row * ldo + (col ^ ((row & 7) << 3))] = f2h(v);
                } else {
                    short hb = f2h(ftanh(v)); // GNN outer tanh
                    S[row * 128 + (col ^ ((row & 7) << 3))] = hb;
                    S[16384 + col * 128 + (row ^ ((col & 7) << 3))] = hb;
                }
            }
        }
    }
}

__global__ void __launch_bounds__(256) k_gin(
    const short* __restrict__ xh, const short* __restrict__ xmh,
    const short* __restrict__ adjT, const short* __restrict__ pertT,
    const short* __restrict__ WT,
    const float* __restrict__ ba, const float* __restrict__ bb, const float* __restrict__ bc,
    const float* __restrict__ mW1, const float* __restrict__ mb1,
    const float* __restrict__ mW2, const float* __restrict__ mb2,
    const float* __restrict__ mW3, const float* __restrict__ mb3,
    float* __restrict__ out)
{
    __shared__ short S[65536]; // 128 KB
    __shared__ float aux[160];
    const int bid = blockIdx.x;
    const int run = bid % 3, g = bid / 3;
    const int t = threadIdx.x;
    const int w = t >> 6, l = t & 63, lr = l & 15, lh = l >> 4;

    const short* h0 = (run == 2 ? xmh : xh) + g * NPG_ * D_;
    const short* am = (run == 1 ? pertT : adjT) + g * NPG_ * NPG_;

    // load h (node-major, swizzled) and hT (feature-major, swizzled)
    for (int i = t; i < NPG_ * D_ / 8; i += 256) {
        short8 v = *(const short8*)(h0 + i * 8);
        int s0 = i >> 4, d0 = (i & 15) * 8;
        *(short8*)&S[s0 * 128 + (d0 ^ ((s0 & 7) << 3))] = v;
        #pragma unroll
        for (int e = 0; e < 8; e++) {
            int d = d0 + e;
            S[16384 + d * 128 + (s0 ^ ((d & 7) << 3))] = v[e];
        }
    }
    __syncthreads();

    for (int layer = 0; layer < 2; layer++) {
        const short* WaT = WT + layer * 32768;
        const short* WbT = WT + 65536 + layer * 65536;
        const short* WcT = WT + 196608 + layer * 32768;

        // Phase 1: z0 = h + A^T h   (A-op = adjT/pertT rows, B-op = hT rows)
        {
            short8 a[2][4];
            #pragma unroll
            for (int m = 0; m < 2; m++) {
                int row = w * 32 + m * 16 + lr;
                #pragma unroll
                for (int ks = 0; ks < 4; ks++)
                    a[m][ks] = *(const short8*)(am + row * 128 + ks * 32 + lh * 8);
            }
            for (int nt = 0; nt < 8; nt++) {
                int col = nt * 16 + lr;
                f32x4 acc0 = {0.f, 0.f, 0.f, 0.f}, acc1 = {0.f, 0.f, 0.f, 0.f};
                #pragma unroll
                for (int ks = 0; ks < 4; ks++) {
                    half8 bfr = __builtin_bit_cast(half8,
                        *(const short8*)&S[16384 + col * 128 + ((ks * 32 + lh * 8) ^ ((col & 7) << 3))]);
                    acc0 = __builtin_amdgcn_mfma_f32_16x16x32_f16(__builtin_bit_cast(half8, a[0][ks]), bfr, acc0, 0, 0, 0);
                    acc1 = __builtin_amdgcn_mfma_f32_16x16x32_f16(__builtin_bit_cast(half8, a[1][ks]), bfr, acc1, 0, 0, 0);
                }
                #pragma unroll
                for (int m = 0; m < 2; m++) {
                    f32x4 acc = m ? acc1 : acc0;
                    #pragma unroll
                    for (int r = 0; r < 4; r++) {
                        int row = w * 32 + m * 16 + lh * 4 + r;
                        float z = h2f(S[row * 128 + (col ^ ((row & 7) << 3))]) + acc[r];
                        S[32768 + row * 128 + (col ^ ((row & 7) << 3))] = f2h(z);
                    }
                }
            }
        }
        __syncthreads();
        fc_phase<4, 256, 0>(S, 32768, 128, 0, 256, WaT, ba + layer * 256, w, lr, lh);
        __syncthreads();
        fc_phase<8, 256, 0>(S, 0, 256, 32768, 256, WbT, bb + layer * 256, w, lr, lh);
        __syncthreads();
        fc_phase<8, 128, 1>(S, 32768, 256, 0, 128, WcT, bc + layer * 128, w, lr, lh);
        __syncthreads();
    }

    // mean-pool over 128 nodes (exact /128), then 3-layer MLP in f32
    if (t < 128) {
        float s = 0.f;
        for (int n = 0; n < 128; n++)
            s += h2f(S[n * 128 + (t ^ ((n & 7) << 3))]);
        aux[t] = s * 0.0078125f;
    }
    __syncthreads();
    if (t < 16) {
        float a = mb1[t];
        for (int d = 0; d < 128; d++) a += aux[d] * mW1[d * 16 + t];
        aux[128 + t] = ftanh(a);
    }
    __syncthreads();
    if (t < 8) {
        float a = mb2[t];
        #pragma unroll
        for (int d = 0; d < 16; d++) a += aux[128 + d] * mW2[d * 8 + t];
        aux[144 + t] = ftanh(a);
    }
    __syncthreads();
    if (t < 2) {
        float a = mb3[t];
        #pragma unroll
        for (int d = 0; d < 8; d++) a += aux[144 + d] * mW3[d * 2 + t];
        out[OUT_PRED + (size_t)run * 96 + g * 2 + t] = ftanh(a);
    }
}

// ---------------------------------------------------------------------------
extern "C" void kernel_launch(void* const* d_in, const int* in_sizes, int n_in,
                              void* d_out, int out_size, void* d_ws, size_t ws_size,
                              hipStream_t stream)
{
    (void)in_sizes; (void)n_in; (void)out_size; (void)ws_size;

    const float* x   = (const float*)d_in[0];
    const int*   ei  = (const int*)d_in[1];
    const float* P   = (const float*)d_in[3];
    const float* Bp  = (const float*)d_in[4];
    const float* M   = (const float*)d_in[5];
    const float* Wa  = (const float*)d_in[6];
    const float* ba  = (const float*)d_in[7];
    const float* Wb  = (const float*)d_in[8];
    const float* bb  = (const float*)d_in[9];
    const float* Wc  = (const float*)d_in[10];
    const float* bc  = (const float*)d_in[11];
    const float* mW1 = (const float*)d_in[12];
    const float* mb1 = (const float*)d_in[13];
    const float* mW2 = (const float*)d_in[14];
    const float* mb2 = (const float*)d_in[15];
    const float* mW3 = (const float*)d_in[16];
    const float* mb3 = (const float*)d_in[17];
    float* out = (float*)d_out;

    char* ws = (char*)d_ws;
    short*         adjT  = (short*)(ws + 0);        // 1,572,864 B
    short*         pertT = (short*)(ws + 1572864);  // 1,572,864 B
    unsigned char* a8    = (unsigned char*)(ws + 3145728); // 786,432 B
    short*         xhp   = (short*)(ws + 3932160);  // 1,572,864 B
    short*         xmh   = (short*)(ws + 5505024);  // 1,572,864 B
    short*         WT    = (short*)(ws + 7077888);  // 524,288 B

    // zero the two NxN f32 maps (kernels write only the diagonal blocks)
    hipMemsetAsync(d_out, 0, 301989888ull, stream);

    k_wt  <<<1024, 256, 0, stream>>>(Wa, Wb, Wc, WT);
    k_adj <<<48,   256, 0, stream>>>(ei, out, adjT, a8);
    k_pert<<<384,  256, 0, stream>>>(P, Bp, a8, out + OUT_PERT, pertT);
    k_mask<<<768,  256, 0, stream>>>(x, M, out + OUT_MASK, xhp, xmh);
    k_gin <<<144,  256, 0, stream>>>(xhp, xmh, adjT, pertT, WT, ba, bb, bc,
                                     mW1, mb1, mW2, mb2, mW3, mb3, out);
}

// Round 3
// 237.983 us; speedup vs baseline: 1.0927x; 1.0927x over previous
//
#include <hip/hip_runtime.h>

#define G_    48
#define NPG_  128
#define NTOT_ 6144
#define D_    128
#define EPG_  4096
#define ETOT_ 196608

// element offsets into f32 d_out
#define OUT_ADJ  0ull
#define OUT_PERT 37748736ull
#define OUT_MASK 75497472ull
#define OUT_PRED 76283904ull

using short8 = __attribute__((ext_vector_type(8))) short;
using half8  = __attribute__((ext_vector_type(8))) _Float16;
using f32x4  = __attribute__((ext_vector_type(4))) float;
using float4v = __attribute__((ext_vector_type(4))) float;

__device__ __forceinline__ short f2h(float f) {
    _Float16 h = (_Float16)f;
    return __builtin_bit_cast(short, h);
}
__device__ __forceinline__ float h2f(short s) {
    _Float16 h = __builtin_bit_cast(_Float16, s);
    return (float)h;
}
__device__ __forceinline__ float ftanh(float x) {
    float ax = fabsf(x);
    float e = __expf(-2.0f * ax);
    float r = (1.0f - e) / (1.0f + e);
    return copysignf(r, x);
}

// ---------------------------------------------------------------------------
// Fast zero-fill of the two NxN f32 maps (replaces runtime fillBuffer @1.6TB/s)
// ---------------------------------------------------------------------------
__global__ void __launch_bounds__(256) k_zero(float4v* __restrict__ p, long n4)
{
    long i = (long)blockIdx.x * 256 + threadIdx.x;
    const long stride = (long)gridDim.x * 256;
    const float4v z = {0.f, 0.f, 0.f, 0.f};
    for (; i < n4; i += stride)
        __builtin_nontemporal_store(z, p + i);
}

// ---------------------------------------------------------------------------
// Adjacency: per-graph LDS histogram -> f32 diag block of adjs_dense,
// fp16 adjT (adjT[g][d][s] = A[s][d]) and u8 counts for k_pert.
// ---------------------------------------------------------------------------
__global__ void __launch_bounds__(256) k_adj(const int* __restrict__ ei,
                                             float* __restrict__ out,
                                             short* __restrict__ adjT,
                                             unsigned char* __restrict__ a8)
{
    __shared__ unsigned int A[NPG_ * NPG_]; // 64 KB
    const int g = blockIdx.x, t = threadIdx.x;
    for (int i = t; i < NPG_ * NPG_; i += 256) A[i] = 0u;
    __syncthreads();
    const int* srcp = ei + g * EPG_;
    const int* dstp = ei + ETOT_ + g * EPG_;
    const int base = g * NPG_;
    for (int i = t; i < EPG_; i += 256) {
        int s = srcp[i] - base;
        int d = dstp[i] - base;
        atomicAdd(&A[s * NPG_ + d], 1u);
    }
    __syncthreads();
    for (int i = t; i < NPG_ * NPG_; i += 256) {
        int r = i >> 7, c = i & 127;
        unsigned int cnt = A[i];
        out[OUT_ADJ + (size_t)(base + r) * NTOT_ + base + c] = (float)cnt;
        adjT[g * NPG_ * NPG_ + c * NPG_ + r] = f2h((float)cnt); // exact (small ints)
        a8[g * NPG_ * NPG_ + i] = (unsigned char)cnt;
    }
}

// ---------------------------------------------------------------------------
// Perturbed adjacency: S = P_g @ A_g + Bp_g accumulated in f64 (sign-exact);
// pert_adj = (S > 0). Writes f32 0/1 + fp16 transposed copy for k_gin.
// ---------------------------------------------------------------------------
__global__ void __launch_bounds__(256) k_pert(const float* __restrict__ P,
                                              const float* __restrict__ Bp,
                                              const unsigned char* __restrict__ a8,
                                              float* __restrict__ out1,
                                              short* __restrict__ pertT)
{
    __shared__ unsigned char sA[NPG_ * NPG_]; // 16 KB, [k][j]
    const int g = blockIdx.x >> 3;
    const int i0 = (blockIdx.x & 7) * 16;
    const int t = threadIdx.x;
    const unsigned char* a = a8 + g * NPG_ * NPG_;
    for (int i = t * 4; i < NPG_ * NPG_; i += 1024)
        *(unsigned int*)&sA[i] = *(const unsigned int*)(a + i);
    __syncthreads();
    const int i = i0 + (t >> 4);
    const int j0 = (t & 15) * 8;
    const float* Prow = P + ((size_t)g * NPG_ + i) * NPG_;
    const float* Brow = Bp + ((size_t)g * NPG_ + i) * NPG_ + j0;
    double acc[8];
    #pragma unroll
    for (int jj = 0; jj < 8; jj++) acc[jj] = (double)Brow[jj];
    for (int k = 0; k < NPG_; k++) {
        double p = (double)Prow[k];
        const unsigned char* ar = &sA[k * NPG_ + j0];
        #pragma unroll
        for (int jj = 0; jj < 8; jj++) acc[jj] += p * (double)ar[jj];
    }
    const size_t obase = (size_t)(g * NPG_ + i) * NTOT_ + g * NPG_ + j0;
    #pragma unroll
    for (int jj = 0; jj < 8; jj++) {
        bool one = (acc[jj] > 0.0);
        out1[obase + jj] = one ? 1.0f : 0.0f;
        pertT[g * NPG_ * NPG_ + (j0 + jj) * NPG_ + i] = one ? (short)0x3C00 : (short)0;
    }
}

// ---------------------------------------------------------------------------
// mask = (M > 0) f32; also emit fp16 x and fp16 x_masked for the GIN runs.
// ---------------------------------------------------------------------------
__global__ void __launch_bounds__(256) k_mask(const float* __restrict__ x,
                                              const float* __restrict__ M,
                                              float* __restrict__ outm,
                                              short* __restrict__ xh,
                                              short* __restrict__ xmh)
{
    int idx = blockIdx.x * 256 + threadIdx.x;
    if (idx >= NTOT_ * D_ / 4) return;
    float4v mv = *(const float4v*)(M + idx * 4);
    float4v xv = *(const float4v*)(x + idx * 4);
    float4v om;
    short hx[4], hm[4];
    #pragma unroll
    for (int e = 0; e < 4; e++) {
        bool pos = (mv[e] > 0.0f);
        om[e] = pos ? 1.0f : 0.0f;
        hx[e] = f2h(xv[e]);
        hm[e] = pos ? hx[e] : (short)0;
    }
    *(float4v*)(outm + idx * 4) = om;
    *(unsigned long long*)(xh + idx * 4)  = *(unsigned long long*)hx;
    *(unsigned long long*)(xmh + idx * 4) = *(unsigned long long*)hm;
}

// ---------------------------------------------------------------------------
// Weight transpose+convert: WT(fp16) = [WaT(2,256,128)|WbT(2,256,256)|WcT(2,128,256)]
// ---------------------------------------------------------------------------
__global__ void __launch_bounds__(256) k_wt(const float* __restrict__ Wa,
                                            const float* __restrict__ Wb,
                                            const float* __restrict__ Wc,
                                            short* __restrict__ WT)
{
    int idx = blockIdx.x * 256 + threadIdx.x;
    if (idx < 65536) {                       // WaT[l][n<256][k<128] = Wa[l][k][n]
        int l = idx >> 15, r = idx & 32767;
        int n = r >> 7, k = r & 127;
        WT[idx] = f2h(Wa[l * 32768 + k * 256 + n]);
    } else if (idx < 196608) {               // WbT[l][n<256][k<256] = Wb[l][k][n]
        int j = idx - 65536;
        int l = j >> 16, r = j & 65535;
        int n = r >> 8, k = r & 255;
        WT[idx] = f2h(Wb[l * 65536 + k * 256 + n]);
    } else if (idx < 262144) {               // WcT[l][n<128][k<256] = Wc[l][k][n]
        int j = idx - 196608;
        int l = j >> 15, r = j & 32767;
        int n = r >> 8, k = r & 255;
        WT[idx] = f2h(Wc[l * 32768 + k * 128 + n]);
    }
}

// ---------------------------------------------------------------------------
// Fused GIN per (graph, run). 512 threads / 8 waves (2 waves/SIMD), 128 KB LDS.
// Each wave owns 16 output rows. LDS map (shorts): h[0,16384) hT[16384,32768)
// z0/t2 [32768,65536)  t1 -> [0,32768).
// XOR swizzle on all tiles: k ^= (row&7)<<3.
// MFMA 16x16x32_f16: A row=lane&15, k=(lane>>4)*8+e; B col=lane&15, same k;
// C/D col=lane&15, row=(lane>>4)*4+reg.
// ---------------------------------------------------------------------------
template<int KS, int NN, int MODE>
__device__ __forceinline__ void fc_phase(short* S, int aoff, int lda, int outoff, int ldo,
                                         const short* __restrict__ BT,
                                         const float* __restrict__ bias,
                                         int w, int lr, int lh)
{
    short8 a[KS];
    const int arow = w * 16 + lr;
    #pragma unroll
    for (int ks = 0; ks < KS; ks++)
        a[ks] = *(const short8*)&S[aoff + arow * lda + ((ks * 32 + lh * 8) ^ ((arow & 7) << 3))];
    for (int nt = 0; nt < NN / 16; nt++) {
        int col = nt * 16 + lr;
        f32x4 acc = {0.f, 0.f, 0.f, 0.f};
        #pragma unroll
        for (int ks = 0; ks < KS; ks++) {
            half8 bfr = __builtin_bit_cast(half8, *(const short8*)(BT + col * (KS * 32) + ks * 32 + lh * 8));
            acc = __builtin_amdgcn_mfma_f32_16x16x32_f16(__builtin_bit_cast(half8, a[ks]), bfr, acc, 0, 0, 0);
        }
        float bv = bias[col];
        #pragma unroll
        for (int r = 0; r < 4; r++) {
            int row = w * 16 + lh * 4 + r;
            float v = ftanh(acc[r] + bv);
            if (MODE == 0) {
                S[outoff + row * ldo + (col ^ ((row & 7) << 3))] = f2h(v);
            } else {
                short hb = f2h(ftanh(v)); // GNN outer tanh
                S[row * 128 + (col ^ ((row & 7) << 3))] = hb;
                S[16384 + col * 128 + (row ^ ((col & 7) << 3))] = hb;
            }
        }
    }
}

__global__ void __launch_bounds__(512) k_gin(
    const short* __restrict__ xh, const short* __restrict__ xmh,
    const short* __restrict__ adjT, const short* __restrict__ pertT,
    const short* __restrict__ WT,
    const float* __restrict__ ba, const float* __restrict__ bb, const float* __restrict__ bc,
    const float* __restrict__ mW1, const float* __restrict__ mb1,
    const float* __restrict__ mW2, const float* __restrict__ mb2,
    const float* __restrict__ mW3, const float* __restrict__ mb3,
    float* __restrict__ out)
{
    __shared__ short S[65536]; // 128 KB
    __shared__ float aux[160];
    const int bid = blockIdx.x;
    const int run = bid % 3, g = bid / 3;
    const int t = threadIdx.x;
    const int w = t >> 6, l = t & 63, lr = l & 15, lh = l >> 4;

    const short* h0 = (run == 2 ? xmh : xh) + g * NPG_ * D_;
    const short* am = (run == 1 ? pertT : adjT) + g * NPG_ * NPG_;

    // load h (node-major, swizzled) and hT (feature-major, swizzled)
    for (int i = t; i < NPG_ * D_ / 8; i += 512) {
        short8 v = *(const short8*)(h0 + i * 8);
        int s0 = i >> 4, d0 = (i & 15) * 8;
        *(short8*)&S[s0 * 128 + (d0 ^ ((s0 & 7) << 3))] = v;
        #pragma unroll
        for (int e = 0; e < 8; e++) {
            int d = d0 + e;
            S[16384 + d * 128 + (s0 ^ ((d & 7) << 3))] = v[e];
        }
    }
    __syncthreads();

    for (int layer = 0; layer < 2; layer++) {
        const short* WaT = WT + layer * 32768;
        const short* WbT = WT + 65536 + layer * 65536;
        const short* WcT = WT + 196608 + layer * 32768;

        // Phase 1: z0 = h + A^T h   (A-op = adjT/pertT rows, B-op = hT rows)
        {
            short8 a[4];
            const int arow = w * 16 + lr;
            #pragma unroll
            for (int ks = 0; ks < 4; ks++)
                a[ks] = *(const short8*)(am + arow * 128 + ks * 32 + lh * 8);
            for (int nt = 0; nt < 8; nt++) {
                int col = nt * 16 + lr;
                f32x4 acc = {0.f, 0.f, 0.f, 0.f};
                #pragma unroll
                for (int ks = 0; ks < 4; ks++) {
                    half8 bfr = __builtin_bit_cast(half8,
                        *(const short8*)&S[16384 + col * 128 + ((ks * 32 + lh * 8) ^ ((col & 7) << 3))]);
                    acc = __builtin_amdgcn_mfma_f32_16x16x32_f16(__builtin_bit_cast(half8, a[ks]), bfr, acc, 0, 0, 0);
                }
                #pragma unroll
                for (int r = 0; r < 4; r++) {
                    int row = w * 16 + lh * 4 + r;
                    float z = h2f(S[row * 128 + (col ^ ((row & 7) << 3))]) + acc[r];
                    S[32768 + row * 128 + (col ^ ((row & 7) << 3))] = f2h(z);
                }
            }
        }
        __syncthreads();
        fc_phase<4, 256, 0>(S, 32768, 128, 0, 256, WaT, ba + layer * 256, w, lr, lh);
        __syncthreads();
        fc_phase<8, 256, 0>(S, 0, 256, 32768, 256, WbT, bb + layer * 256, w, lr, lh);
        __syncthreads();
        fc_phase<8, 128, 1>(S, 32768, 256, 0, 128, WcT, bc + layer * 128, w, lr, lh);
        __syncthreads();
    }

    // mean-pool over 128 nodes (exact /128), then 3-layer MLP in f32
    if (t < 128) {
        float s = 0.f;
        for (int n = 0; n < 128; n++)
            s += h2f(S[n * 128 + (t ^ ((n & 7) << 3))]);
        aux[t] = s * 0.0078125f;
    }
    __syncthreads();
    if (t < 16) {
        float a = mb1[t];
        for (int d = 0; d < 128; d++) a += aux[d] * mW1[d * 16 + t];
        aux[128 + t] = ftanh(a);
    }
    __syncthreads();
    if (t < 8) {
        float a = mb2[t];
        #pragma unroll
        for (int d = 0; d < 16; d++) a += aux[128 + d] * mW2[d * 8 + t];
        aux[144 + t] = ftanh(a);
    }
    __syncthreads();
    if (t < 2) {
        float a = mb3[t];
        #pragma unroll
        for (int d = 0; d < 8; d++) a += aux[144 + d] * mW3[d * 2 + t];
        out[OUT_PRED + (size_t)run * 96 + g * 2 + t] = ftanh(a);
    }
}

// ---------------------------------------------------------------------------
extern "C" void kernel_launch(void* const* d_in, const int* in_sizes, int n_in,
                              void* d_out, int out_size, void* d_ws, size_t ws_size,
                              hipStream_t stream)
{
    (void)in_sizes; (void)n_in; (void)out_size; (void)ws_size;

    const float* x   = (const float*)d_in[0];
    const int*   ei  = (const int*)d_in[1];
    const float* P   = (const float*)d_in[3];
    const float* Bp  = (const float*)d_in[4];
    const float* M   = (const float*)d_in[5];
    const float* Wa  = (const float*)d_in[6];
    const float* ba  = (const float*)d_in[7];
    const float* Wb  = (const float*)d_in[8];
    const float* bb  = (const float*)d_in[9];
    const float* Wc  = (const float*)d_in[10];
    const float* bc  = (const float*)d_in[11];
    const float* mW1 = (const float*)d_in[12];
    const float* mb1 = (const float*)d_in[13];
    const float* mW2 = (const float*)d_in[14];
    const float* mb2 = (const float*)d_in[15];
    const float* mW3 = (const float*)d_in[16];
    const float* mb3 = (const float*)d_in[17];
    float* out = (float*)d_out;

    char* ws = (char*)d_ws;
    short*         adjT  = (short*)(ws + 0);        // 1,572,864 B
    short*         pertT = (short*)(ws + 1572864);  // 1,572,864 B
    unsigned char* a8    = (unsigned char*)(ws + 3145728); // 786,432 B
    short*         xhp   = (short*)(ws + 3932160);  // 1,572,864 B
    short*         xmh   = (short*)(ws + 5505024);  // 1,572,864 B
    short*         WT    = (short*)(ws + 7077888);  // 524,288 B

    // zero the two NxN f32 maps (kernels then overwrite the diagonal blocks)
    k_zero<<<3072, 256, 0, stream>>>((float4v*)d_out, 301989888ll / 16);

    k_wt  <<<1024, 256, 0, stream>>>(Wa, Wb, Wc, WT);
    k_adj <<<48,   256, 0, stream>>>(ei, out, adjT, a8);
    k_pert<<<384,  256, 0, stream>>>(P, Bp, a8, out + OUT_PERT, pertT);
    k_mask<<<768,  256, 0, stream>>>(x, M, out + OUT_MASK, xhp, xmh);
    k_gin <<<144,  512, 0, stream>>>(xhp, xmh, adjT, pertT, WT, ba, bb, bc,
                                     mW1, mb1, mW2, mb2, mW3, mb3, out);
}

// Round 4
// 189.870 us; speedup vs baseline: 1.3696x; 1.2534x over previous
//
#include <hip/hip_runtime.h>

#define G_    48
#define NPG_  128
#define NTOT_ 6144
#define D_    128
#define EPG_  4096
#define ETOT_ 196608

// element offsets into f32 d_out
#define OUT_ADJ  0ull
#define OUT_PERT 37748736ull
#define OUT_MASK 75497472ull
#define OUT_PRED 76283904ull

using short8 = __attribute__((ext_vector_type(8))) short;
using half8  = __attribute__((ext_vector_type(8))) _Float16;
using f32x4  = __attribute__((ext_vector_type(4))) float;
using float4v = __attribute__((ext_vector_type(4))) float;

__device__ __forceinline__ short f2h(float f) {
    _Float16 h = (_Float16)f;
    return __builtin_bit_cast(short, h);
}
__device__ __forceinline__ float h2f(short s) {
    _Float16 h = __builtin_bit_cast(_Float16, s);
    return (float)h;
}
__device__ __forceinline__ float ftanh(float x) {
    float ax = fabsf(x);
    float e = __expf(-2.0f * ax);
    float r = (1.0f - e) / (1.0f + e);
    return copysignf(r, x);
}

// ---------------------------------------------------------------------------
// k_pre: fused adj-histogram (blocks 0..47), weight transpose (48..303),
// mask + fp16 x / x_masked (304..1071). All parts independent.
// ---------------------------------------------------------------------------
__global__ void __launch_bounds__(256) k_pre(const int* __restrict__ ei,
                                             const float* __restrict__ x,
                                             const float* __restrict__ M,
                                             const float* __restrict__ Wa,
                                             const float* __restrict__ Wb,
                                             const float* __restrict__ Wc,
                                             float* __restrict__ out,
                                             short* __restrict__ adjT,
                                             unsigned char* __restrict__ a8,
                                             short* __restrict__ xh,
                                             short* __restrict__ xmh,
                                             short* __restrict__ WT)
{
    __shared__ unsigned int A[NPG_ * NPG_]; // 64 KB (adj blocks only)
    const int bid = blockIdx.x, t = threadIdx.x;
    if (bid < 48) {
        const int g = bid;
        for (int i = t; i < NPG_ * NPG_; i += 256) A[i] = 0u;
        __syncthreads();
        const int* srcp = ei + g * EPG_;
        const int* dstp = ei + ETOT_ + g * EPG_;
        const int base = g * NPG_;
        for (int i = t; i < EPG_; i += 256) {
            int s = srcp[i] - base;
            int d = dstp[i] - base;
            atomicAdd(&A[s * NPG_ + d], 1u);
        }
        __syncthreads();
        for (int i = t; i < NPG_ * NPG_; i += 256) {
            int r = i >> 7, c = i & 127;
            unsigned int cnt = A[i];
            out[OUT_ADJ + (size_t)(base + r) * NTOT_ + base + c] = (float)cnt;
            adjT[g * NPG_ * NPG_ + c * NPG_ + r] = f2h((float)cnt); // exact small ints
            a8[g * NPG_ * NPG_ + i] = (unsigned char)cnt;
        }
    } else if (bid < 304) {
        const int wtb = bid - 48;
        #pragma unroll
        for (int e = 0; e < 4; e++) {
            int idx = wtb * 1024 + e * 256 + t;
            if (idx < 65536) {                       // WaT[l][n<256][k<128] = Wa[l][k][n]
                int l = idx >> 15, r = idx & 32767;
                int n = r >> 7, k = r & 127;
                WT[idx] = f2h(Wa[l * 32768 + k * 256 + n]);
            } else if (idx < 196608) {               // WbT[l][n<256][k<256] = Wb[l][k][n]
                int j = idx - 65536;
                int l = j >> 16, r = j & 65535;
                int n = r >> 8, k = r & 255;
                WT[idx] = f2h(Wb[l * 65536 + k * 256 + n]);
            } else {                                 // WcT[l][n<128][k<256] = Wc[l][k][n]
                int j = idx - 196608;
                int l = j >> 15, r = j & 32767;
                int n = r >> 8, k = r & 255;
                WT[idx] = f2h(Wc[l * 32768 + k * 128 + n]);
            }
        }
    } else {
        int idx = (bid - 304) * 256 + t;             // < 196608
        float4v mv = *(const float4v*)(M + idx * 4);
        float4v xv = *(const float4v*)(x + idx * 4);
        float4v om;
        short hx[4], hm[4];
        #pragma unroll
        for (int e = 0; e < 4; e++) {
            bool pos = (mv[e] > 0.0f);
            om[e] = pos ? 1.0f : 0.0f;
            hx[e] = f2h(xv[e]);
            hm[e] = pos ? hx[e] : (short)0;
        }
        *(float4v*)(out + OUT_MASK + idx * 4) = om;
        *(unsigned long long*)(xh + idx * 4)  = *(unsigned long long*)hx;
        *(unsigned long long*)(xmh + idx * 4) = *(unsigned long long*)hm;
    }
}

// ---------------------------------------------------------------------------
// Perturbed adjacency: S = P_g @ A_g + Bp_g accumulated in f64 (sign-exact);
// pert_adj = (S > 0). Writes f32 0/1 diag block + fp16 transposed copy.
// ---------------------------------------------------------------------------
__global__ void __launch_bounds__(256) k_pert(const float* __restrict__ P,
                                              const float* __restrict__ Bp,
                                              const unsigned char* __restrict__ a8,
                                              float* __restrict__ out1,
                                              short* __restrict__ pertT)
{
    __shared__ unsigned char sA[NPG_ * NPG_]; // 16 KB, [k][j]
    const int g = blockIdx.x >> 3;
    const int i0 = (blockIdx.x & 7) * 16;
    const int t = threadIdx.x;
    const unsigned char* a = a8 + g * NPG_ * NPG_;
    for (int i = t * 4; i < NPG_ * NPG_; i += 1024)
        *(unsigned int*)&sA[i] = *(const unsigned int*)(a + i);
    __syncthreads();
    const int i = i0 + (t >> 4);
    const int j0 = (t & 15) * 8;
    const float* Prow = P + ((size_t)g * NPG_ + i) * NPG_;
    const float* Brow = Bp + ((size_t)g * NPG_ + i) * NPG_ + j0;
    double acc[8];
    #pragma unroll
    for (int jj = 0; jj < 8; jj++) acc[jj] = (double)Brow[jj];
    for (int k = 0; k < NPG_; k++) {
        double p = (double)Prow[k];
        const unsigned char* ar = &sA[k * NPG_ + j0];
        #pragma unroll
        for (int jj = 0; jj < 8; jj++) acc[jj] += p * (double)ar[jj];
    }
    const size_t obase = (size_t)(g * NPG_ + i) * NTOT_ + g * NPG_ + j0;
    #pragma unroll
    for (int jj = 0; jj < 8; jj++) {
        bool one = (acc[jj] > 0.0);
        out1[obase + jj] = one ? 1.0f : 0.0f;
        pertT[g * NPG_ * NPG_ + (j0 + jj) * NPG_ + i] = one ? (short)0x3C00 : (short)0;
    }
}

// ---------------------------------------------------------------------------
// k_main: blocks 0..143 = fused GIN (64 KB LDS, h in registers, in-place
// fc phases); blocks 144..3215 = off-diagonal zero-fill of the two NxN maps
// (plain dwordx4 stores). Fill overlaps GIN across CUs.
//
// GIN LDS map (shorts): hT [0,16384)  z0 [16384,32768)
//   fc1: reads z0 (regs) -> t1 over [0,32768)
//   fc2: in-place on [0,32768)
//   fc3: reads (regs) -> writes new hT [0,16384) + hreg (f32, per-thread)
// Every fc phase barriers between its register A-load and its first write.
// ---------------------------------------------------------------------------
template<int KS, int NN, int MODE>
__device__ __forceinline__ void fc_phase(short* S, int aoff, int lda, int outoff, int ldo,
                                         const short* __restrict__ BT,
                                         const float* __restrict__ bias,
                                         int w, int lr, int lh, float* hreg)
{
    short8 a[KS];
    const int arow = w * 16 + lr;
    #pragma unroll
    for (int ks = 0; ks < KS; ks++)
        a[ks] = *(const short8*)&S[aoff + arow * lda + ((ks * 32 + lh * 8) ^ ((arow & 7) << 3))];
    __syncthreads(); // all A-fragments in regs before any in-place write
    for (int nt = 0; nt < NN / 16; nt++) {
        int col = nt * 16 + lr;
        f32x4 acc = {0.f, 0.f, 0.f, 0.f};
        #pragma unroll
        for (int ks = 0; ks < KS; ks++) {
            half8 bfr = __builtin_bit_cast(half8, *(const short8*)(BT + col * (KS * 32) + ks * 32 + lh * 8));
            acc = __builtin_amdgcn_mfma_f32_16x16x32_f16(__builtin_bit_cast(half8, a[ks]), bfr, acc, 0, 0, 0);
        }
        float bv = bias[col];
        #pragma unroll
        for (int r = 0; r < 4; r++) {
            int row = w * 16 + lh * 4 + r;
            float v = ftanh(acc[r] + bv);
            if (MODE == 0) {
                S[outoff + row * ldo + (col ^ ((row & 7) << 3))] = f2h(v);
            } else {
                float th = ftanh(v);                 // GNN outer tanh
                S[col * 128 + (row ^ ((col & 7) << 3))] = f2h(th); // new hT
                hreg[nt * 4 + r] = th;
            }
        }
    }
}

__global__ void __launch_bounds__(512) k_main(
    const short* __restrict__ xh, const short* __restrict__ xmh,
    const short* __restrict__ adjT, const short* __restrict__ pertT,
    const short* __restrict__ WT,
    const float* __restrict__ ba, const float* __restrict__ bb, const float* __restrict__ bc,
    const float* __restrict__ mW1, const float* __restrict__ mb1,
    const float* __restrict__ mW2, const float* __restrict__ mb2,
    const float* __restrict__ mW3, const float* __restrict__ mb3,
    float* __restrict__ out)
{
    __shared__ short S[32768]; // 64 KB
    __shared__ float aux[160];
    const int bid = blockIdx.x;
    const int t = threadIdx.x;

    if (bid >= 144) {
        // ---- zero-fill: 4 rows per block, 2 maps x 6144 rows, skip diag block
        const int fid = bid - 144;                   // [0,3072)
        float4v* p = (float4v*)out;
        const float4v z = {0.f, 0.f, 0.f, 0.f};
        #pragma unroll
        for (int q = 0; q < 4; q++) {
            int cr = fid * 4 + q;                    // [0,12288)
            int m  = cr >= 6144;
            int r  = cr - (m ? 6144 : 0);
            int gr = r >> 7;
            size_t base4 = ((m ? OUT_PERT : OUT_ADJ) >> 2) + (size_t)r * 1536;
            int dlo = gr * 32, dhi = dlo + 32;
            #pragma unroll
            for (int it = 0; it < 3; it++) {
                int s = it * 512 + t;
                if (s < dlo || s >= dhi) p[base4 + s] = z;
            }
        }
        return;
    }

    // ---- GIN part
    const int run = bid % 3, g = bid / 3;
    const int w = t >> 6, l = t & 63, lr = l & 15, lh = l >> 4;

    const short* h0 = (run == 2 ? xmh : xh) + g * NPG_ * D_;
    const short* am = (run == 1 ? pertT : adjT) + g * NPG_ * NPG_;

    // hT init: hT[d][s] = x[s][d], swizzled within row d
    for (int i = t; i < NPG_ * D_ / 8; i += 512) {
        short8 v = *(const short8*)(h0 + i * 8);
        int s0 = i >> 4, d0 = (i & 15) * 8;
        #pragma unroll
        for (int e = 0; e < 8; e++) {
            int d = d0 + e;
            S[d * 128 + (s0 ^ ((d & 7) << 3))] = v[e];
        }
    }
    __syncthreads();

    // hreg: per-thread h values at this thread's C-layout positions (f32)
    float hreg[32];
    #pragma unroll
    for (int nt = 0; nt < 8; nt++)
        #pragma unroll
        for (int r = 0; r < 4; r++) {
            int col = nt * 16 + lr, row = w * 16 + lh * 4 + r;
            hreg[nt * 4 + r] = h2f(S[col * 128 + (row ^ ((col & 7) << 3))]);
        }

    for (int layer = 0; layer < 2; layer++) {
        const short* WaT = WT + layer * 32768;
        const short* WbT = WT + 65536 + layer * 65536;
        const short* WcT = WT + 196608 + layer * 32768;

        // Phase 1: z0 = h + A^T h  (A-op = adjT/pertT rows global, B-op = hT)
        {
            short8 a[4];
            const int arow = w * 16 + lr;
            #pragma unroll
            for (int ks = 0; ks < 4; ks++)
                a[ks] = *(const short8*)(am + arow * 128 + ks * 32 + lh * 8);
            for (int nt = 0; nt < 8; nt++) {
                int col = nt * 16 + lr;
                f32x4 acc = {0.f, 0.f, 0.f, 0.f};
                #pragma unroll
                for (int ks = 0; ks < 4; ks++) {
                    half8 bfr = __builtin_bit_cast(half8,
                        *(const short8*)&S[col * 128 + ((ks * 32 + lh * 8) ^ ((col & 7) << 3))]);
                    acc = __builtin_amdgcn_mfma_f32_16x16x32_f16(__builtin_bit_cast(half8, a[ks]), bfr, acc, 0, 0, 0);
                }
                #pragma unroll
                for (int r = 0; r < 4; r++) {
                    int row = w * 16 + lh * 4 + r;
                    float zv = hreg[nt * 4 + r] + acc[r];
                    S[16384 + row * 128 + (col ^ ((row & 7) << 3))] = f2h(zv);
                }
            }
        }
        __syncthreads();
        fc_phase<4, 256, 0>(S, 16384, 128, 0, 256, WaT, ba + layer * 256, w, lr, lh, hreg);
        __syncthreads();
        fc_phase<8, 256, 0>(S, 0, 256, 0, 256, WbT, bb + layer * 256, w, lr, lh, hreg);
        __syncthreads();
        fc_phase<8, 128, 1>(S, 0, 256, 0, 128, WcT, bc + layer * 128, w, lr, lh, hreg);
        __syncthreads();
    }

    // mean-pool per feature from hT rows (rotated order: bank-spread, sum-equal)
    if (t < 128) {
        float s = 0.f;
        for (int nn = 0; nn < 128; nn++)
            s += h2f(S[t * 128 + ((nn + t) & 127)]);
        aux[t] = s * 0.0078125f;
    }
    __syncthreads();
    if (t < 16) {
        float a = mb1[t];
        for (int d = 0; d < 128; d++) a += aux[d] * mW1[d * 16 + t];
        aux[128 + t] = ftanh(a);
    }
    __syncthreads();
    if (t < 8) {
        float a = mb2[t];
        #pragma unroll
        for (int d = 0; d < 16; d++) a += aux[128 + d] * mW2[d * 8 + t];
        aux[144 + t] = ftanh(a);
    }
    __syncthreads();
    if (t < 2) {
        float a = mb3[t];
        #pragma unroll
        for (int d = 0; d < 8; d++) a += aux[144 + d] * mW3[d * 2 + t];
        out[OUT_PRED + (size_t)run * 96 + g * 2 + t] = ftanh(a);
    }
}

// ---------------------------------------------------------------------------
extern "C" void kernel_launch(void* const* d_in, const int* in_sizes, int n_in,
                              void* d_out, int out_size, void* d_ws, size_t ws_size,
                              hipStream_t stream)
{
    (void)in_sizes; (void)n_in; (void)out_size; (void)ws_size;

    const float* x   = (const float*)d_in[0];
    const int*   ei  = (const int*)d_in[1];
    const float* P   = (const float*)d_in[3];
    const float* Bp  = (const float*)d_in[4];
    const float* M   = (const float*)d_in[5];
    const float* Wa  = (const float*)d_in[6];
    const float* ba  = (const float*)d_in[7];
    const float* Wb  = (const float*)d_in[8];
    const float* bb  = (const float*)d_in[9];
    const float* Wc  = (const float*)d_in[10];
    const float* bc  = (const float*)d_in[11];
    const float* mW1 = (const float*)d_in[12];
    const float* mb1 = (const float*)d_in[13];
    const float* mW2 = (const float*)d_in[14];
    const float* mb2 = (const float*)d_in[15];
    const float* mW3 = (const float*)d_in[16];
    const float* mb3 = (const float*)d_in[17];
    float* out = (float*)d_out;

    char* ws = (char*)d_ws;
    short*         adjT  = (short*)(ws + 0);        // 1,572,864 B
    short*         pertT = (short*)(ws + 1572864);  // 1,572,864 B
    unsigned char* a8    = (unsigned char*)(ws + 3145728); // 786,432 B
    short*         xhp   = (short*)(ws + 3932160);  // 1,572,864 B
    short*         xmh   = (short*)(ws + 5505024);  // 1,572,864 B
    short*         WT    = (short*)(ws + 7077888);  // 524,288 B

    k_pre <<<1072, 256, 0, stream>>>(ei, x, M, Wa, Wb, Wc, out, adjT, a8, xhp, xmh, WT);
    k_pert<<<384,  256, 0, stream>>>(P, Bp, a8, out + OUT_PERT, pertT);
    k_main<<<3216, 512, 0, stream>>>(xhp, xmh, adjT, pertT, WT, ba, bb, bc,
                                     mW1, mb1, mW2, mb2, mW3, mb3, out);
}